// Round 14
// baseline (494.565 us; speedup 1.0000x reference)
//
#include <hip/hip_runtime.h>

#define T_DIM 4096
#define J_DIM 24
#define NCI 16
#define NCO 16
#define G_DIM 75
#define WAVE_T 256            // t-elements per wave (64 lanes x 4)
#define TILE_T (WAVE_T * 4)   // t-elements per block (4 waves)
#define ROW_STRIDE ((size_t)J_DIM * T_DIM)

// Inverse of ALL_IDX: for each original joint j, the output g-positions that
// replicate it (conv kernel height is 1, so gathered rows are pure copies).
__device__ const int d_nrep[J_DIM] = {4,3,3,3,3,3,3,3,3,5,3,3,3,3,3,3,3,3,3,3,3,3,3,3};
__device__ const int d_repl[J_DIM][5] = {
  {0, 9, 12, 15, -1},
  {1, 10, 18, -1, -1},
  {2, 13, 21, -1, -1},
  {3, 16, 24, -1, -1},
  {11, 19, 27, -1, -1},
  {14, 22, 30, -1, -1},
  {17, 25, 33, -1, -1},
  {20, 28, 38, -1, -1},
  {23, 31, 40, -1, -1},
  {26, 34, 42, 45, 48},
  {4, 29, 39, -1, -1},
  {5, 32, 41, -1, -1},
  {35, 43, 51, -1, -1},
  {36, 46, 53, -1, -1},
  {37, 49, 56, -1, -1},
  {6, 44, 52, -1, -1},
  {47, 54, 59, -1, -1},
  {50, 57, 62, -1, -1},
  {55, 60, 65, -1, -1},
  {58, 63, 68, -1, -1},
  {61, 66, 71, -1, -1},
  {64, 69, 73, -1, -1},
  {7, 67, 72, -1, -1},
  {8, 70, 74, -1, -1},
};

__global__ __launch_bounds__(256, 4) void skel_conv(
    const float* __restrict__ x, const float* __restrict__ W,
    const float* __restrict__ bias, float* __restrict__ out) {
  const int tile = blockIdx.x;   // block t-tile (4 tiles of 1024)
  const int j    = blockIdx.y;   // original joint
  const int b    = blockIdx.z;   // batch
  const int tid  = (int)threadIdx.x;
  const int lane = tid & 63;
  // Each WAVE owns a private 256-t slice and computes ALL 16 out-channels
  // -> no two waves anywhere read the same x cache line.
  const int wv = __builtin_amdgcn_readfirstlane(tid >> 6);

  const int t0 = tile * TILE_T + wv * WAVE_T + lane * 4;
  const float* xb = x + ((size_t)b * NCI * J_DIM + j) * T_DIM;

  // 1) All 16 x-row loads issued up front: 16 independent VMEM ops in
  //    flight (deep read pipeline). Fully unrolled -> static indices.
  float4 xr[NCI];
#pragma unroll
  for (int ci = 0; ci < NCI; ++ci)
    xr[ci] = *(const float4*)(xb + ci * ROW_STRIDE + t0);

  // 2) All halos once: 32 shuffles + two divergent patch regions total.
  float xm[NCI], xp[NCI];
#pragma unroll
  for (int ci = 0; ci < NCI; ++ci) {
    xm[ci] = __shfl_up(xr[ci].w, 1);    // x[t0-1]
    xp[ci] = __shfl_down(xr[ci].x, 1);  // x[t0+4]
  }
  if (lane == 0) {
#pragma unroll
    for (int ci = 0; ci < NCI; ++ci)
      xm[ci] = (t0 > 0) ? xb[ci * ROW_STRIDE + t0 - 1] : 0.f;
  }
  if (lane == 63) {
#pragma unroll
    for (int ci = 0; ci < NCI; ++ci)
      xp[ci] = (t0 + 4 < T_DIM) ? xb[ci * ROW_STRIDE + t0 + 4] : 0.f;
  }

  // 3) co-outer / ci-inner: each co's 3-5 stores issue as soon as its
  //    accumulator completes -> stores spread evenly through compute.
  //    Per-co weights are 48 contiguous floats -> batched s_loads.
  const int nrep = d_nrep[j];
  float* ob = out + (size_t)b * NCO * G_DIM * T_DIM + t0;
#pragma unroll
  for (int co = 0; co < NCO; ++co) {
    const float bb = bias[co];
    float4 a = make_float4(bb, bb, bb, bb);
#pragma unroll
    for (int ci = 0; ci < NCI; ++ci) {
      const float w0 = W[(co * NCI + ci) * 3 + 0];
      const float w1 = W[(co * NCI + ci) * 3 + 1];
      const float w2 = W[(co * NCI + ci) * 3 + 2];
      const float4 v = xr[ci];
      a.x = fmaf(xm[ci], w0, fmaf(v.x, w1, fmaf(v.y, w2, a.x)));
      a.y = fmaf(v.x,    w0, fmaf(v.y, w1, fmaf(v.z, w2, a.y)));
      a.z = fmaf(v.y,    w0, fmaf(v.z, w1, fmaf(v.w, w2, a.z)));
      a.w = fmaf(v.z,    w0, fmaf(v.w, w1, fmaf(xp[ci], w2, a.w)));
    }
    float* oc = ob + (size_t)co * (G_DIM * T_DIM);
    for (int r = 0; r < nrep; ++r) {
      const int g = d_repl[j][r];
      *(float4*)(oc + (size_t)g * T_DIM) = a;
    }
  }
}

extern "C" void kernel_launch(void* const* d_in, const int* in_sizes, int n_in,
                              void* d_out, int out_size, void* d_ws, size_t ws_size,
                              hipStream_t stream) {
  const float* x    = (const float*)d_in[0];
  const float* W    = (const float*)d_in[1];
  const float* bias = (const float*)d_in[2];
  float* out = (float*)d_out;

  dim3 grid(T_DIM / TILE_T, J_DIM, 32);  // 4 x 24 x 32 = 3072 blocks
  dim3 block(256);
  skel_conv<<<grid, block, 0, stream>>>(x, W, bias, out);
}

// Round 15
// 175.652 us; speedup vs baseline: 2.8156x; 2.8156x over previous
//
#include <hip/hip_runtime.h>

#define T_DIM 4096
#define J_DIM 24
#define NCI 16
#define NCO 16
#define G_DIM 75
#define WAVE_T 256            // t-elements per wave slice (64 lanes x 4)
#define TILE_T 512            // per block: 2 t-slices x 2 co-halves

// Inverse of ALL_IDX: for each original joint j, the output g-positions that
// replicate it (conv kernel height is 1, so gathered rows are pure copies).
__device__ const int d_nrep[J_DIM] = {4,3,3,3,3,3,3,3,3,5,3,3,3,3,3,3,3,3,3,3,3,3,3,3};
__device__ const int d_repl[J_DIM][5] = {
  {0, 9, 12, 15, -1},
  {1, 10, 18, -1, -1},
  {2, 13, 21, -1, -1},
  {3, 16, 24, -1, -1},
  {11, 19, 27, -1, -1},
  {14, 22, 30, -1, -1},
  {17, 25, 33, -1, -1},
  {20, 28, 38, -1, -1},
  {23, 31, 40, -1, -1},
  {26, 34, 42, 45, 48},
  {4, 29, 39, -1, -1},
  {5, 32, 41, -1, -1},
  {35, 43, 51, -1, -1},
  {36, 46, 53, -1, -1},
  {37, 49, 56, -1, -1},
  {6, 44, 52, -1, -1},
  {47, 54, 59, -1, -1},
  {50, 57, 62, -1, -1},
  {55, 60, 65, -1, -1},
  {58, 63, 68, -1, -1},
  {61, 66, 71, -1, -1},
  {64, 69, 73, -1, -1},
  {7, 67, 72, -1, -1},
  {8, 70, 74, -1, -1},
};

// 8 co per wave, <=64 VGPR -> 8 waves/SIMD (32 waves/CU), 2x R13 occupancy.
// The 2 waves sharing a t-slice (co-halves) are in the same block/CU and
// issue the same x loads back-to-back -> second read is an L1/L2 hit, no
// HBM re-fetch (R2's 4-way drift-share failure mode avoided).
__global__ __launch_bounds__(256, 8) void skel_conv(
    const float* __restrict__ x, const float* __restrict__ W,
    const float* __restrict__ bias, float* __restrict__ out) {
  const int tile = blockIdx.x;   // block t-tile (8 tiles of 512)
  const int j    = blockIdx.y;   // original joint
  const int b    = blockIdx.z;   // batch
  const int tid  = (int)threadIdx.x;
  const int lane = tid & 63;
  const int wv   = __builtin_amdgcn_readfirstlane(tid >> 6);
  const int coh  = wv & 1;       // co-half: 0 -> co 0..7, 1 -> co 8..15
  const int th   = wv >> 1;      // t-slice within block
  const int co0  = coh * 8;

  const int t0 = tile * TILE_T + th * WAVE_T + lane * 4;

  // acc[cc] for co = co0+cc (8 x float4 = 32 VGPR), init with bias
  float4 acc[8];
#pragma unroll
  for (int cc = 0; cc < 8; ++cc) {
    const float bb = bias[co0 + cc];
    acc[cc] = make_float4(bb, bb, bb, bb);
  }

#pragma unroll 2
  for (int ci = 0; ci < NCI; ++ci) {
    const float* xp = x + (((size_t)b * NCI + ci) * J_DIM + j) * T_DIM;
    const float4 v = *(const float4*)(xp + t0);
    // t-halo via in-wave shuffle; wave-edge lanes patch with a direct load
    float xm1 = __shfl_up(v.w, 1);    // x[t0-1]
    float xp4 = __shfl_down(v.x, 1);  // x[t0+4]
    if (lane == 0)  xm1 = (t0 > 0) ? xp[t0 - 1] : 0.f;
    if (lane == 63) xp4 = (t0 + 4 < T_DIM) ? xp[t0 + 4] : 0.f;

#pragma unroll
    for (int cc = 0; cc < 8; ++cc) {
      // wave-uniform indices -> s_load; SGPR operands in the FMAs
      const float w0 = W[((co0 + cc) * NCI + ci) * 3 + 0];
      const float w1 = W[((co0 + cc) * NCI + ci) * 3 + 1];
      const float w2 = W[((co0 + cc) * NCI + ci) * 3 + 2];
      acc[cc].x = fmaf(xm1, w0, fmaf(v.x, w1, fmaf(v.y, w2, acc[cc].x)));
      acc[cc].y = fmaf(v.x, w0, fmaf(v.y, w1, fmaf(v.z, w2, acc[cc].y)));
      acc[cc].z = fmaf(v.y, w0, fmaf(v.z, w1, fmaf(v.w, w2, acc[cc].z)));
      acc[cc].w = fmaf(v.z, w0, fmaf(v.w, w1, fmaf(xp4, w2, acc[cc].w)));
    }
  }

  // Lockstep store phase (R13 win): waves enter together; co-outer order.
  __syncthreads();

  const int nrep = d_nrep[j];
  float* ob = out + (((size_t)b * NCO + co0) * G_DIM) * T_DIM + t0;
#pragma unroll
  for (int cc = 0; cc < 8; ++cc) {
    float* oc = ob + (size_t)cc * (G_DIM * T_DIM);
    for (int r = 0; r < nrep; ++r) {
      const int g = d_repl[j][r];
      *(float4*)(oc + (size_t)g * T_DIM) = acc[cc];
    }
  }
}

extern "C" void kernel_launch(void* const* d_in, const int* in_sizes, int n_in,
                              void* d_out, int out_size, void* d_ws, size_t ws_size,
                              hipStream_t stream) {
  const float* x    = (const float*)d_in[0];
  const float* W    = (const float*)d_in[1];
  const float* bias = (const float*)d_in[2];
  float* out = (float*)d_out;

  dim3 grid(T_DIM / TILE_T, J_DIM, 32);  // 8 x 24 x 32 = 6144 blocks
  dim3 block(256);
  skel_conv<<<grid, block, 0, stream>>>(x, W, bias, out);
}